// Round 10
// baseline (98.312 us; speedup 1.0000x reference)
//
#include <hip/hip_runtime.h>

// NEAT windowed-DAG forward, R16: quad-split + static slots + asm fma_mix.
//   values[0:16] = x; for i in 0..511: v = tanh(dot(values[i:i+16], w[i]) + b[i]) * r[i]
//   out = values[T-64:T]
//
// Model (R6-R15): per-wave wall/node = max(own issue, serial chain ~98cyc
// [fma->exp2->add->rcp, trans dep ~45]) + slip. Stall at 2 w/SIMD = 78 vs
// 104 at 1 w/SIMD -> cross-wave hiding works; R15 lost because its NODE
// compiled to ~30 instr (casts didn't fold to fma_mix; dpp migration).
// R16 = 2 waves/SIMD with issue FORCED to 13 instr/node:
//  * inline-asm v_fma_mix_f32 (op_sel picks the f16 half) -- no cvts.
//  * STATIC tap slots: taps never move; staged weights are PRE-ROTATED
//    per node (slot p of node n holds w"[n][(p-n+15)%16], stale slot = 0).
//    Window update = ONE cndmask (insert u_{k-1} into stale slot, owner
//    lane only), replacing R15's dpp+cndmask migration.
//  * injection (R11/R14): u_{k-1} enters via post-reduce fma(up,w15,s);
//    insert is off-chain (consumed from node k+1; weight-0 at node k makes
//    read/insert order irrelevant).
// Numerics identical to R14 (f16 weights RNE, f32 taps, u-domain).
//
// Slots: s=0..15, lane jq = s>>2, reg = s&3 (r0..r3). u_j lives in slot
// j%16 from its insert (during node j+1) until overwritten (node j+17).
// Insert schedule: node k writes up=u_{k-1} into slot (k-1)%16.
// Region record (8 nodes, 512 B): weight pair m=0..3 at m*64 + jq*16:
// b128 = node 2m (slots 4jq..4jq+3, 4 f16 = 8 B) then node 2m+1 (8 B).
// Meta chunk c=0..3 at 256 + c*64 + jq*16 (4-replica): f32x4 =
// (Bq_{2c}, w15_{2c}, Bq_{2c+1}, w15_{2c+1}); Bq = B"/4 (4-lane reduce
// restores B"). 8 ds_read_b128/region, depth-1 dbuf, counted lgkmcnt(8).

typedef float v4f __attribute__((ext_vector_type(4)));

constexpr int   kNOut   = 64;
constexpr int   kBatch  = 32768;
constexpr int   kRegB   = 512;                    // bytes per 8-node region
constexpr int   kLdsFloats = 65 * 128;            // 64 regions + 1 overrun pad
constexpr float kScale  = 2.8853900817779268f;    // 2*log2(e)

// quad_perm DPP through the builtin so the compiler handles hazard nops.
#define QPERM(X, CTRL) __int_as_float(__builtin_amdgcn_update_dpp(            \
    __float_as_int(X), __float_as_int(X), (CTRL), 0xF, 0xF, false))

__device__ __forceinline__ unsigned pack2(float lo, float hi) {
    _Float16 l = (_Float16)lo, h = (_Float16)hi;    // RNE converts
    unsigned short ul = __builtin_bit_cast(unsigned short, l);
    unsigned short uh = __builtin_bit_cast(unsigned short, h);
    return ((unsigned)uh << 16) | ul;
}

// 8 ds_read_b128 for region set S (4 weight pairs + 4 meta chunks).
// All addresses are 4-way (one per jq) x 16-lane broadcast -> conflict-free.
#define PREF(S) {                                                             \
    asm volatile(                                                             \
      "ds_read_b128 %0, %8 offset:0\n\t"                                      \
      "ds_read_b128 %1, %8 offset:64\n\t"                                     \
      "ds_read_b128 %2, %8 offset:128\n\t"                                    \
      "ds_read_b128 %3, %8 offset:192\n\t"                                    \
      "ds_read_b128 %4, %8 offset:256\n\t"                                    \
      "ds_read_b128 %5, %8 offset:320\n\t"                                    \
      "ds_read_b128 %6, %8 offset:384\n\t"                                    \
      "ds_read_b128 %7, %8 offset:448"                                        \
      : "=&v"(qw0[S]), "=&v"(qw1[S]), "=&v"(qw2[S]), "=&v"(qw3[S]),           \
        "=&v"(qm0[S]), "=&v"(qm1[S]), "=&v"(qm2[S]), "=&v"(qm3[S])            \
      : "v"(a));                                                              \
    a += kRegB; }

// Depth-1 dbuf: waiting for set S, only the other set's 8 reads are newer;
// in-order DS returns make lgkmcnt(8) == "set S landed".
#define WAITR(S)                                                              \
    asm volatile("s_waitcnt lgkmcnt(8)"                                       \
      : "+v"(qw0[S]), "+v"(qw1[S]), "+v"(qw2[S]), "+v"(qw3[S]),               \
        "+v"(qm0[S]), "+v"(qm1[S]), "+v"(qm2[S]), "+v"(qm3[S]));

// Forced mixed-precision fma: D(f32) = f16half(W)*T(f32) + C(f32).
#define FMIXL(D, W, T, C)                                                     \
    asm("v_fma_mix_f32 %0, %1, %2, %3 op_sel:[0,0,0] op_sel_hi:[1,0,0]"       \
        : "=v"(D) : "v"(W), "v"(T), "v"(C));
#define FMIXH(D, W, T, C)                                                     \
    asm("v_fma_mix_f32 %0, %1, %2, %3 op_sel:[1,0,0] op_sel_hi:[1,0,0]"       \
        : "=v"(D) : "v"(W), "v"(T), "v"(C));

// One node. W0 holds f16 weights of slots {4jq,4jq+1}, W1 of {4jq+2,4jq+3}
// (pre-rotated so each slot's weight matches its resident value; the stale
// slot's weight is 0). BQ = B"/4. Chain: inject fma -> exp2 -> add -> rcp.
// Insert: up (=u_{k-1}) into the stale slot's reg, owner lane only.
#define NODE(W0, W1, BQ, W15, OWN, TREG) {                                    \
    float p0, p1, p2, p3;                                                     \
    FMIXL(p0, (W0), r0, (BQ))                                                 \
    FMIXH(p1, (W0), r1, p0)                                                   \
    FMIXL(p2, (W1), r2, p1)                                                   \
    FMIXH(p3, (W1), r3, p2)                                                   \
    float s1 = p3 + QPERM(p3, 0xB1);        /* quad_perm:[1,0,3,2] */         \
    float s2 = s1 + QPERM(s1, 0x4E);        /* quad_perm:[2,3,0,1] */         \
    float ac = fmaf(up, (W15), s2);         /* chain starts here */           \
    float ex = __builtin_amdgcn_exp2f(ac);                                    \
    float un = __builtin_amdgcn_rcpf(ex + 1.0f);                              \
    (TREG) = (OWN) ? up : (TREG);           /* off-chain insert */            \
    up = un; }

// Regions: A covers node offsets d=0..7 of a 16-node supercycle, B covers
// d=8..15. Insert target for node d: slot (d+15)%16 -> (owner, reg).
#define REGA(SP, SC) {                                                        \
    PREF(SP)                                                                  \
    WAITR(SC)                                                                 \
    NODE(qw0[SC][0], qw0[SC][1], qm0[SC][0], qm0[SC][1], o3, r3)              \
    NODE(qw0[SC][2], qw0[SC][3], qm0[SC][2], qm0[SC][3], o0, r0)              \
    NODE(qw1[SC][0], qw1[SC][1], qm1[SC][0], qm1[SC][1], o0, r1)              \
    NODE(qw1[SC][2], qw1[SC][3], qm1[SC][2], qm1[SC][3], o0, r2)              \
    NODE(qw2[SC][0], qw2[SC][1], qm2[SC][0], qm2[SC][1], o0, r3)              \
    NODE(qw2[SC][2], qw2[SC][3], qm2[SC][2], qm2[SC][3], o1, r0)              \
    NODE(qw3[SC][0], qw3[SC][1], qm3[SC][0], qm3[SC][1], o1, r1)              \
    NODE(qw3[SC][2], qw3[SC][3], qm3[SC][2], qm3[SC][3], o1, r2) }
#define REGB(SP, SC) {                                                        \
    PREF(SP)                                                                  \
    WAITR(SC)                                                                 \
    NODE(qw0[SC][0], qw0[SC][1], qm0[SC][0], qm0[SC][1], o1, r3)              \
    NODE(qw0[SC][2], qw0[SC][3], qm0[SC][2], qm0[SC][3], o2, r0)              \
    NODE(qw1[SC][0], qw1[SC][1], qm1[SC][0], qm1[SC][1], o2, r1)              \
    NODE(qw1[SC][2], qw1[SC][3], qm1[SC][2], qm1[SC][3], o2, r2)              \
    NODE(qw2[SC][0], qw2[SC][1], qm2[SC][0], qm2[SC][1], o2, r3)              \
    NODE(qw2[SC][2], qw2[SC][3], qm2[SC][2], qm2[SC][3], o3, r0)              \
    NODE(qw3[SC][0], qw3[SC][1], qm3[SC][0], qm3[SC][1], o3, r1)              \
    NODE(qw3[SC][2], qw3[SC][3], qm3[SC][2], qm3[SC][3], o3, r2) }

__global__ __launch_bounds__(512) void neat_fwd(
    const float* __restrict__ x,      // [B, 16]
    const float* __restrict__ w,      // [512, 16]
    const float* __restrict__ bias,   // [512]
    const float* __restrict__ resp,   // [512]
    float* __restrict__ out)          // [B, 64]
{
    __shared__ alignas(16) float ldsw[kLdsFloats];
    __shared__ float rst[512];
    __shared__ float tmp[512 * 16];   // staging rotation buffer (one-time)

    const int t  = threadIdx.x;       // 0..511 (8 waves)
    const int jq = t & 3;             // lane within quad
    const bool o0 = (jq == 0), o1 = (jq == 1), o2 = (jq == 2), o3 = (jq == 3);

    // ---- Stage: raw resp ----
    rst[t] = resp[t];
    __syncthreads();

    // ---- Stage node n = t: pre-rotated f16 weights + meta ----
    {
        const int n = t;
        const float4* wn = reinterpret_cast<const float4*>(w) + n * 4;
        float4 a0 = wn[0], a1 = wn[1], a2 = wn[2], a3 = wn[3];
        const float m2k = -2.0f * kScale;
        float sum = 0.0f;
        float ws0,ws1,ws2,ws3,ws4,ws5,ws6,ws7,ws8,ws9,ws10,ws11,ws12,ws13,ws14,ws15;
        #define DO(J, V) { float rho = (n + (J) < 16) ? 1.0f : rst[n + (J) - 16]; \
                           float wr = (V) * rho; sum += wr; ws##J = wr * m2k; }
        DO(0,a0.x)  DO(1,a0.y)  DO(2,a0.z)  DO(3,a0.w)
        DO(4,a1.x)  DO(5,a1.y)  DO(6,a1.z)  DO(7,a1.w)
        DO(8,a2.x)  DO(9,a2.y)  DO(10,a2.z) DO(11,a2.w)
        DO(12,a3.x) DO(13,a3.y) DO(14,a3.z) DO(15,a3.w)
        #undef DO
        // rotate: source j -> slot (n+j)%16 (j=0..14); slot (n+15)%16 = 0.
        float* tb = tmp + t * 16;
        tb[(n + 15) & 15] = 0.0f;
        #define PUT(J) tb[(n + (J)) & 15] = ws##J;
        PUT(0) PUT(1) PUT(2) PUT(3) PUT(4) PUT(5) PUT(6) PUT(7)
        PUT(8) PUT(9) PUT(10) PUT(11) PUT(12) PUT(13) PUT(14)
        #undef PUT
        const int sg = n >> 3, d = n & 7, m = d >> 1, h = d & 1;
        unsigned* lu = reinterpret_cast<unsigned*>(ldsw);
        const int wbase = sg * 128 + m * 16 + h * 2;    // u32 index
        #pragma unroll
        for (int q = 0; q < 4; ++q) {
            lu[wbase + q * 4 + 0] = pack2(tb[4*q + 0], tb[4*q + 1]);
            lu[wbase + q * 4 + 1] = pack2(tb[4*q + 2], tb[4*q + 3]);
        }
        const float Bq = (bias[n] + sum) * (kScale * 0.25f);
        const int fbase = sg * 128 + 64 + m * 16 + h * 2;  // float index
        #pragma unroll
        for (int q = 0; q < 4; ++q) {
            ldsw[fbase + q * 4]     = Bq;
            ldsw[fbase + q * 4 + 1] = ws15;     // injection weight (f32)
        }
    }

    // ---- Per-thread taps: slot p holds enc(x_p) initially; up = enc(x15) ----
    const int e = blockIdx.x * 128 + (t >> 2);     // batch element
    const float4 xi = reinterpret_cast<const float4*>(x)[e * 4 + jq];
    float r0 = fmaf(-0.5f, xi.x, 0.5f);    // u = (1-x)/2 (exact affine)
    float r1 = fmaf(-0.5f, xi.y, 0.5f);
    float r2 = fmaf(-0.5f, xi.z, 0.5f);
    float r3 = fmaf(-0.5f, xi.w, 0.5f);
    float up = fmaf(-0.5f, x[(size_t)e * 16 + 15], 0.5f);   // u_{-1}

    const float4* __restrict__ rr4 = reinterpret_cast<const float4*>(resp);
    float* __restrict__ op = out + (size_t)e * kNOut + jq * 4;

    __syncthreads();   // drains staging ds ops (compiler lgkmcnt(0))

    // DS byte cursor (+ lane's 16B block offset folded in).
    unsigned int a = (unsigned int)(unsigned long long)(&ldsw[0])
                   + (unsigned int)(jq << 4);

    v4f qw0[2], qw1[2], qw2[2], qw3[2], qm0[2], qm1[2], qm2[2], qm3[2];
    PREF(0)                       // region 0 in flight

    #pragma unroll 1
    for (int g = 0; g < 32; ++g) {
        REGA(1, 0)                // nodes 16g+0..7   (consume set 0)
        REGB(0, 1)                // nodes 16g+8..15  (consume set 1)
        // End of supercycle: slot p (p<=14) = u_{16g+p}; up = u_{16g+15};
        // lane3's r3 (slot 15) is stale -> substitute up.
        if (g >= 28) {
            const int m_ = g - 28;
            const float4 rv = rr4[112 + 4 * m_ + jq];
            float v3 = o3 ? up : r3;
            *reinterpret_cast<float4*>(op + 16 * m_) =
                make_float4(fmaf(-2.0f, r0, 1.0f) * rv.x,
                            fmaf(-2.0f, r1, 1.0f) * rv.y,
                            fmaf(-2.0f, r2, 1.0f) * rv.z,
                            fmaf(-2.0f, v3, 1.0f) * rv.w);
        }
    }

    // Drain the overrun prefetch (pad region 64).
    asm volatile("s_waitcnt lgkmcnt(0)" ::: "memory");
}

extern "C" void kernel_launch(void* const* d_in, const int* in_sizes, int n_in,
                              void* d_out, int out_size, void* d_ws, size_t ws_size,
                              hipStream_t stream) {
    const float* x    = (const float*)d_in[0];
    const float* w    = (const float*)d_in[1];
    const float* bias = (const float*)d_in[2];
    const float* resp = (const float*)d_in[3];
    float* out = (float*)d_out;
    // in_sizes[4] (src_idx) encodes the fixed windowed topology; hardcoded above.
    dim3 block(512);
    dim3 grid(kBatch * 4 / 512);   // 256 blocks -> 1/CU, 8 waves/CU = 2 per SIMD
    hipLaunchKernelGGL(neat_fwd, grid, block, 0, stream, x, w, bias, resp, out);
}

// Round 11
// 89.926 us; speedup vs baseline: 1.0933x; 1.0933x over previous
//
#include <hip/hip_runtime.h>

// NEAT windowed-DAG forward, R17: R14 (best, ~150 cyc/node) + forced v_fma_mix.
//   values[0:16] = x; for i in 0..511: v = tanh(dot(values[i:i+16], w[i]) + b[i]) * r[i]
//   out = values[T-64:T]
//
// Ledger: quad-split @2w/SIMD falsified 3x (R7/R15/R16: 214/200/215 cyc/node
// -- structure carries ~2x hidden issue: DPP hazards, masks, asm moves).
// Chain algebra null (R8/R11). Delivery path null (R12/R13). Fences -6% (R14).
// Best = R14: pair-split, 1 w/SIMD, 8-node regions, injection, f16 weights.
// R14's one known defect: (float)wh[i] casts emit cvt bloat (R15 evidence)
// instead of folding to v_fma_mix_f32. R17 = R14 with the 8 tap-fmas forced
// to inline-asm v_fma_mix_f32 (op_sel selects f16 half; no cvts). Single
// variable; everything else byte-identical.
//
// Numerics (R11+R13+R14 verified): u-domain u = sigmoid(-2z); w" =
// -2*kScale*w*rho (f16 RNE); delayed insert -- lane1's newest tap is
// u_{k-2}; u_{k-1} enters only via post-reduce inject fma(UIN, W15, s);
// chain = fma->exp2->add->rcp. lane0 taps u_{k-16+m} w/ w"[0..7]; lane1
// taps u_{k-9+m} w/ [0, w8..w14] (zero pad on oldest); meta (Bh, w15) f32.
// Inputs u=(1-x)/2; outputs o = rho*(1-2u).
//
// Supergroup record (8 nodes, 384 B): node s weights at s*32 (+16*jl lane
// half, 8 packed f16); meta chunks m=0..3 at 256+m*32 (+16*jl replica):
// b128 = (Bh_{2m}, w15_{2m}, Bh_{2m+1}, w15_{2m+1}).
// 12 ds_read_b128/region, depth-1 dbuf, exact counted lgkmcnt(12).

typedef float v4f __attribute__((ext_vector_type(4)));

constexpr int   kNOut   = 64;
constexpr int   kBatch  = 32768;
constexpr int   kSgF    = 96;                     // floats per supergroup (384 B)
constexpr int   kSgB    = 384;
constexpr int   kLdsFloats = 65 * kSgF;           // 64 supergroups + 1 pad (overrun)
constexpr float kScale  = 2.8853900817779268f;    // 2*log2(e)

// quad_perm DPP through the builtin so the compiler handles hazard nops.
#define QPERM(X, CTRL) __int_as_float(__builtin_amdgcn_update_dpp(            \
    __float_as_int(X), __float_as_int(X), (CTRL), 0xF, 0xF, false))

__device__ __forceinline__ unsigned pack2(float lo, float hi) {
    _Float16 l = (_Float16)lo, h = (_Float16)hi;    // RNE converts
    unsigned short ul = __builtin_bit_cast(unsigned short, l);
    unsigned short uh = __builtin_bit_cast(unsigned short, h);
    return ((unsigned)uh << 16) | ul;
}

// Forced mixed-precision fma: D(f32) = f16(lo/hi of W) * T(f32) + C(f32).
#define FMIXL(D, W, T, C)                                                     \
    asm("v_fma_mix_f32 %0, %1, %2, %3 op_sel:[0,0,0] op_sel_hi:[1,0,0]"       \
        : "=v"(D) : "v"(W), "v"(T), "v"(C));
#define FMIXH(D, W, T, C)                                                     \
    asm("v_fma_mix_f32 %0, %1, %2, %3 op_sel:[1,0,0] op_sel_hi:[1,0,0]"       \
        : "=v"(D) : "v"(W), "v"(T), "v"(C));

// 12 ds_read_b128 for supergroup set S (8 weight + 4 meta); cursor a has
// the lane's +16B half-offset folded in. Lane-pairs read 2 addresses ->
// LDS broadcast, conflict-free.
#define PREF(S) {                                                             \
    asm volatile(                                                             \
      "ds_read_b128 %0, %12 offset:0\n\t"                                     \
      "ds_read_b128 %1, %12 offset:32\n\t"                                    \
      "ds_read_b128 %2, %12 offset:64\n\t"                                    \
      "ds_read_b128 %3, %12 offset:96\n\t"                                    \
      "ds_read_b128 %4, %12 offset:128\n\t"                                   \
      "ds_read_b128 %5, %12 offset:160\n\t"                                   \
      "ds_read_b128 %6, %12 offset:192\n\t"                                   \
      "ds_read_b128 %7, %12 offset:224\n\t"                                   \
      "ds_read_b128 %8, %12 offset:256\n\t"                                   \
      "ds_read_b128 %9, %12 offset:288\n\t"                                   \
      "ds_read_b128 %10, %12 offset:320\n\t"                                  \
      "ds_read_b128 %11, %12 offset:352"                                      \
      : "=&v"(qw0[S]), "=&v"(qw1[S]), "=&v"(qw2[S]), "=&v"(qw3[S]),           \
        "=&v"(qw4[S]), "=&v"(qw5[S]), "=&v"(qw6[S]), "=&v"(qw7[S]),           \
        "=&v"(qm0[S]), "=&v"(qm1[S]), "=&v"(qm2[S]), "=&v"(qm3[S])            \
      : "v"(a));                                                              \
    a += kSgB; }

// Depth-1 dbuf: waiting for set S, only the other set's 12 reads are newer;
// in-order DS returns make lgkmcnt(12) == "set S landed". "+v" ties the
// consumers to this asm (proven R6-R16 pattern).
#define WAITR(S)                                                              \
    asm volatile("s_waitcnt lgkmcnt(12)"                                      \
      : "+v"(qw0[S]), "+v"(qw1[S]), "+v"(qw2[S]), "+v"(qw3[S]),               \
        "+v"(qw4[S]), "+v"(qw5[S]), "+v"(qw6[S]), "+v"(qw7[S]),               \
        "+v"(qm0[S]), "+v"(qm1[S]), "+v"(qm2[S]), "+v"(qm3[S]));

// One node (R14 semantics; fma_mix instead of casts). All 8 partial fmas +
// pair reduce OFF-chain (no tap holds u_{k-1}; lane1's A0 pad weight is 0).
// Chain: acc = fma(UIN, W15, s) -> exp2 -> add -> rcp -> UOUT.
#define NODE1(QW, BH, W15, UIN, UOUT, A0,A1,A2,A3,A4,A5,A6,A7) {              \
    float p0, p1, p2, p3, p4, p5, p6, p7;                                     \
    FMIXL(p0, (QW)[0], (A0), (BH))                                            \
    FMIXH(p1, (QW)[0], (A1), p0)                                              \
    FMIXL(p2, (QW)[1], (A2), p1)                                              \
    FMIXH(p3, (QW)[1], (A3), p2)                                              \
    FMIXL(p4, (QW)[2], (A4), p3)                                              \
    FMIXH(p5, (QW)[2], (A5), p4)                                              \
    FMIXL(p6, (QW)[3], (A6), p5)                                              \
    FMIXH(p7, (QW)[3], (A7), p6)                                              \
    float s_ = p7 + QPERM(p7, 0xB1);        /* quad_perm:[1,0,3,2] */         \
    float mg = QPERM((A1), 0xB1);           /* partner's u_{k-8} */           \
    float acc = fmaf((UIN), (W15), s_);     /* chain starts here */           \
    float exv = __builtin_amdgcn_exp2f(acc);                                  \
    (UOUT) = __builtin_amdgcn_rcpf(exv + 1.0f);                               \
    (A0) = is_l1 ? (UIN) : mg; }

// 8-node region: one prefetch (other set), one counted wait, 8 nodes with
// tap names rotating left (period 8 -> names realign each region).
#define REGION(SP, SC) {                                                      \
    PREF(SP)                                                                  \
    WAITR(SC)                                                                 \
    NODE1(qw0[SC], qm0[SC].x, qm0[SC].y, u0, u1, r0,r1,r2,r3,r4,r5,r6,r7)     \
    NODE1(qw1[SC], qm0[SC].z, qm0[SC].w, u1, u0, r1,r2,r3,r4,r5,r6,r7,r0)     \
    NODE1(qw2[SC], qm1[SC].x, qm1[SC].y, u0, u1, r2,r3,r4,r5,r6,r7,r0,r1)     \
    NODE1(qw3[SC], qm1[SC].z, qm1[SC].w, u1, u0, r3,r4,r5,r6,r7,r0,r1,r2)     \
    NODE1(qw4[SC], qm2[SC].x, qm2[SC].y, u0, u1, r4,r5,r6,r7,r0,r1,r2,r3)     \
    NODE1(qw5[SC], qm2[SC].z, qm2[SC].w, u1, u0, r5,r6,r7,r0,r1,r2,r3,r4)     \
    NODE1(qw6[SC], qm3[SC].x, qm3[SC].y, u0, u1, r6,r7,r0,r1,r2,r3,r4,r5)     \
    NODE1(qw7[SC], qm3[SC].z, qm3[SC].w, u1, u0, r7,r0,r1,r2,r3,r4,r5,r6) }

__global__ __launch_bounds__(256) void neat_fwd(
    const float* __restrict__ x,      // [B, 16]
    const float* __restrict__ w,      // [512, 16]
    const float* __restrict__ bias,   // [512]
    const float* __restrict__ resp,   // [512]
    float* __restrict__ out)          // [B, 64]
{
    __shared__ alignas(16) float ldsw[kLdsFloats];
    __shared__ float rst[512];

    const int t  = threadIdx.x;       // 0..255 (4 waves)
    const int jl = t & 1;             // lane within pair
    const bool is_l1 = (jl == 1);

    // ---- Stage: raw resp first ----
    rst[t] = resp[t];
    rst[t + 256] = resp[t + 256];
    __syncthreads();

    // ---- Stage per node (each thread owns 2 whole nodes) ----
    // w" = -2*kScale*w*rho (f16 RNE); Bh = kScale*(b + sum_j w*rho)/2 (f32);
    // lane0 half [w"0..w"7]; lane1 half [0, w"8..w"14]; meta (Bh, w"15 f32).
    const float4* __restrict__ w4 = reinterpret_cast<const float4*>(w);
    const float m2k = -2.0f * kScale;
    #pragma unroll
    for (int k = 0; k < 2; ++k) {
        int n = t + (k << 8);
        const float4* wn = w4 + n * 4;
        float4 a0 = wn[0], a1 = wn[1], a2 = wn[2], a3 = wn[3];
        float sum = 0.0f;
        float ws0,ws1,ws2,ws3,ws4,ws5,ws6,ws7,ws8,ws9,ws10,ws11,ws12,ws13,ws14,ws15;
        #define DO(J, V) { float rho = (n + (J) < 16) ? 1.0f : rst[n + (J) - 16]; \
                           float wr = (V) * rho; sum += wr; ws##J = wr * m2k; }
        DO(0,a0.x)  DO(1,a0.y)  DO(2,a0.z)  DO(3,a0.w)
        DO(4,a1.x)  DO(5,a1.y)  DO(6,a1.z)  DO(7,a1.w)
        DO(8,a2.x)  DO(9,a2.y)  DO(10,a2.z) DO(11,a2.w)
        DO(12,a3.x) DO(13,a3.y) DO(14,a3.z) DO(15,a3.w)
        #undef DO
        const int sg = n >> 3, s = n & 7;
        float* gb = ldsw + sg * kSgF;
        // weights: lane0 half at byte s*32, lane1 half at +16
        uint4 lo = make_uint4(pack2(ws0, ws1),  pack2(ws2, ws3),
                              pack2(ws4, ws5),  pack2(ws6, ws7));
        uint4 hi = make_uint4(pack2(0.0f, ws8), pack2(ws9, ws10),
                              pack2(ws11,ws12), pack2(ws13,ws14));
        uint4* dst = reinterpret_cast<uint4*>(gb + s * 8);
        dst[0] = lo;
        dst[1] = hi;
        // meta chunk m = s>>1: (Bh,w15) pairs; lane0 at 256+m*32, lane1 +16
        float Bh = (bias[n] + sum) * (kScale * 0.5f);
        int mi = 64 + (s >> 1) * 8 + (s & 1) * 2;   // float index (lane0)
        gb[mi]     = Bh;  gb[mi + 1] = ws15;
        gb[mi + 4] = Bh;  gb[mi + 5] = ws15;        // lane1 replica (+16 B)
    }

    // ---- Per-thread window init (u-encoded inputs), R11/R14 verbatim ----
    // Node 0 taps: lane0 = enc(x0..x7), lane1 = enc(x7..x14); u_prev = enc(x15).
    const int e = blockIdx.x * 128 + (t >> 1);     // batch element
    const float4* __restrict__ x4p = reinterpret_cast<const float4*>(x);
    float4 X0 = x4p[e*4+0], X1 = x4p[e*4+1], X2 = x4p[e*4+2], X3 = x4p[e*4+3];
    float xx0 = fmaf(-0.5f, X0.x, 0.5f), xx1 = fmaf(-0.5f, X0.y, 0.5f);
    float xx2 = fmaf(-0.5f, X0.z, 0.5f), xx3 = fmaf(-0.5f, X0.w, 0.5f);
    float xx4 = fmaf(-0.5f, X1.x, 0.5f), xx5 = fmaf(-0.5f, X1.y, 0.5f);
    float xx6 = fmaf(-0.5f, X1.z, 0.5f), xx7 = fmaf(-0.5f, X1.w, 0.5f);
    float xx8 = fmaf(-0.5f, X2.x, 0.5f), xx9 = fmaf(-0.5f, X2.y, 0.5f);
    float xx10 = fmaf(-0.5f, X2.z, 0.5f), xx11 = fmaf(-0.5f, X2.w, 0.5f);
    float xx12 = fmaf(-0.5f, X3.x, 0.5f), xx13 = fmaf(-0.5f, X3.y, 0.5f);
    float xx14 = fmaf(-0.5f, X3.z, 0.5f), xx15 = fmaf(-0.5f, X3.w, 0.5f);
    float r0 = is_l1 ? xx7  : xx0;
    float r1 = is_l1 ? xx8  : xx1;
    float r2 = is_l1 ? xx9  : xx2;
    float r3 = is_l1 ? xx10 : xx3;
    float r4 = is_l1 ? xx11 : xx4;
    float r5 = is_l1 ? xx12 : xx5;
    float r6 = is_l1 ? xx13 : xx6;
    float r7 = is_l1 ? xx14 : xx7;
    float u0 = xx15;          // u_{-1} (uniform)
    float u1 = 0.0f;

    const float4* __restrict__ rr4 = reinterpret_cast<const float4*>(resp);
    float* __restrict__ op = out + (size_t)e * kNOut + jl * 8;

    __syncthreads();   // drains staging ds ops (compiler lgkmcnt(0))

    // DS byte cursor (+ lane's 16B half-offset folded in).
    unsigned int a = (unsigned int)(unsigned long long)(&ldsw[0])
                   + (unsigned int)(jl << 4);

    v4f qw0[2], qw1[2], qw2[2], qw3[2], qw4[2], qw5[2], qw6[2], qw7[2];
    v4f qm0[2], qm1[2], qm2[2], qm3[2];
    PREF(0)                       // supergroup 0 in flight

    #pragma unroll 1
    for (int g = 0; g < 32; ++g) {
        REGION(1, 0)              // prefetch next 8 nodes, compute current 8
        REGION(0, 1)
        // After 16 nodes (R11 mapping): lane0 r_c = u_{16g+c};
        // lane1 r_{c+1} = u_{16g+8+c}; u_{16g+15} = u0.
        if (g >= 28) {
            int m = g - 28;
            const float4 ra = rr4[112 + 4 * m + 2 * jl];
            const float4 rb = rr4[112 + 4 * m + 2 * jl + 1];
            float o0 = is_l1 ? r1 : r0;
            float o1 = is_l1 ? r2 : r1;
            float o2 = is_l1 ? r3 : r2;
            float o3 = is_l1 ? r4 : r3;
            float o4 = is_l1 ? r5 : r4;
            float o5 = is_l1 ? r6 : r5;
            float o6 = is_l1 ? r7 : r6;
            float o7 = is_l1 ? u0 : r7;
            float4 q0_ = make_float4(fmaf(-2.0f, o0, 1.0f) * ra.x,
                                     fmaf(-2.0f, o1, 1.0f) * ra.y,
                                     fmaf(-2.0f, o2, 1.0f) * ra.z,
                                     fmaf(-2.0f, o3, 1.0f) * ra.w);
            float4 q1_ = make_float4(fmaf(-2.0f, o4, 1.0f) * rb.x,
                                     fmaf(-2.0f, o5, 1.0f) * rb.y,
                                     fmaf(-2.0f, o6, 1.0f) * rb.z,
                                     fmaf(-2.0f, o7, 1.0f) * rb.w);
            *reinterpret_cast<float4*>(op + 16 * m)     = q0_;
            *reinterpret_cast<float4*>(op + 16 * m + 4) = q1_;
        }
    }

    // Drain the overrun prefetch (pad supergroup 64).
    asm volatile("s_waitcnt lgkmcnt(0)" ::: "memory");
}

extern "C" void kernel_launch(void* const* d_in, const int* in_sizes, int n_in,
                              void* d_out, int out_size, void* d_ws, size_t ws_size,
                              hipStream_t stream) {
    const float* x    = (const float*)d_in[0];
    const float* w    = (const float*)d_in[1];
    const float* bias = (const float*)d_in[2];
    const float* resp = (const float*)d_in[3];
    float* out = (float*)d_out;
    // in_sizes[4] (src_idx) encodes the fixed windowed topology; hardcoded above.
    dim3 block(256);
    dim3 grid(kBatch / 128);   // 256 blocks -> 1/CU, 4 waves/CU = 1 per SIMD
    hipLaunchKernelGGL(neat_fwd, grid, block, 0, stream, x, w, bias, resp, out);
}